// Round 6
// baseline (204.774 us; speedup 1.0000x reference)
//
#include <hip/hip_runtime.h>
#include <hip/hip_bf16.h>

// Problem constants (B=1)
#define L_SEQ   2048
#define D_MODEL 512
#define D_INNER 1024
#define D_STATE 16
#define DT_RANK 32

typedef unsigned short u16;
typedef short bf16x8 __attribute__((ext_vector_type(8)));
typedef float f32x4  __attribute__((ext_vector_type(4)));
typedef unsigned short u16x8 __attribute__((ext_vector_type(8)));

__device__ __forceinline__ u16 f2bf(float f) {
    union { float f; unsigned u; } x; x.f = f;
    unsigned r = x.u + 0x7FFFu + ((x.u >> 16) & 1u);
    return (u16)(r >> 16);
}

__device__ __forceinline__ void gload_lds16(const void* g, void* l) {
    __builtin_amdgcn_global_load_lds((const __attribute__((address_space(1))) void*)g,
                                     (__attribute__((address_space(3))) void*)l, 16, 0, 0);
}

// ---------------------------------------------------------------------------
// bf16 MFMA GEMM (NT):  C[m][n] = sum_k A[m*K+k]*B[n*K+k], C f32.  (verified)
// ---------------------------------------------------------------------------
template<int BM, int BN>
__global__ __launch_bounds__(256)
void gemm_mfma_nt(const u16* __restrict__ A, const u16* __restrict__ B,
                  float* __restrict__ C, int M, int N, int K, int ldc) {
    constexpr int FM = BM / 32;
    constexpr int FN = BN / 32;
    __shared__ u16 lA[BM * 64];
    __shared__ u16 lB[BN * 64];

    const int tid  = threadIdx.x;
    const int lane = tid & 63;
    const int w    = tid >> 6;
    const int wr   = w >> 1, wc = w & 1;
    const int m0 = blockIdx.y * BM;
    const int n0 = blockIdx.x * BN;

    f32x4 acc[FM][FN];
#pragma unroll
    for (int m = 0; m < FM; m++)
#pragma unroll
        for (int n = 0; n < FN; n++) acc[m][n] = (f32x4){0.f, 0.f, 0.f, 0.f};

    int offA[FM][2], offB[FN][2];
#pragma unroll
    for (int m = 0; m < FM; m++) {
        int r = wr * (BM / 2) + m * 16 + (lane & 15);
#pragma unroll
        for (int s = 0; s < 2; s++) {
            int kb = s * 4 + (lane >> 4);
            offA[m][s] = r * 128 + ((kb ^ (r & 7)) << 4);
        }
    }
#pragma unroll
    for (int n = 0; n < FN; n++) {
        int r = wc * (BN / 2) + n * 16 + (lane & 15);
#pragma unroll
        for (int s = 0; s < 2; s++) {
            int kb = s * 4 + (lane >> 4);
            offB[n][s] = r * 128 + ((kb ^ (r & 7)) << 4);
        }
    }

    const int ldsbase = (tid & 192) * 16;

    for (int k0 = 0; k0 < K; k0 += 64) {
        __syncthreads();
#pragma unroll
        for (int i = 0; i < BM / 32; i++) {
            int o = i * 4096 + tid * 16;
            int r = o >> 7;
            int kb = ((o >> 4) & 7) ^ (r & 7);
            gload_lds16(A + (size_t)(m0 + r) * K + k0 + kb * 8,
                        (char*)lA + i * 4096 + ldsbase);
        }
#pragma unroll
        for (int i = 0; i < BN / 32; i++) {
            int o = i * 4096 + tid * 16;
            int r = o >> 7;
            int kb = ((o >> 4) & 7) ^ (r & 7);
            gload_lds16(B + (size_t)(n0 + r) * K + k0 + kb * 8,
                        (char*)lB + i * 4096 + ldsbase);
        }
        __syncthreads();

#pragma unroll
        for (int s = 0; s < 2; s++) {
            bf16x8 av[FM], bv[FN];
#pragma unroll
            for (int m = 0; m < FM; m++)
                av[m] = *(const bf16x8*)((const char*)lA + offA[m][s]);
#pragma unroll
            for (int n = 0; n < FN; n++)
                bv[n] = *(const bf16x8*)((const char*)lB + offB[n][s]);
#pragma unroll
            for (int m = 0; m < FM; m++)
#pragma unroll
                for (int n = 0; n < FN; n++)
                    acc[m][n] = __builtin_amdgcn_mfma_f32_16x16x32_bf16(
                        av[m], bv[n], acc[m][n], 0, 0, 0);
        }
    }

    const int rb = (lane >> 4) * 4;
    const int cb = lane & 15;
#pragma unroll
    for (int m = 0; m < FM; m++)
#pragma unroll
        for (int n = 0; n < FN; n++) {
            int col = n0 + wc * (BN / 2) + n * 16 + cb;
#pragma unroll
            for (int j = 0; j < 4; j++) {
                int row = m0 + wr * (BM / 2) + m * 16 + rb + j;
                C[(size_t)row * ldc + col] = acc[m][n][j];
            }
        }
}

// ---------------------------------------------------------------------------
// Fused f32->bf16 cast of x, in_proj_w, out_proj_w.  (unchanged)
// ---------------------------------------------------------------------------
__global__ __launch_bounds__(256)
void cast3_kernel(const float* __restrict__ x, const float* __restrict__ w1,
                  const float* __restrict__ w2,
                  u16* __restrict__ xb, u16* __restrict__ w1b, u16* __restrict__ w2b) {
    int g = blockIdx.x * 256 + threadIdx.x;
    const float* src; u16* dst; int off;
    if (g < 131072)      { src = x;  dst = xb;  off = g; }
    else if (g < 262144) { src = w1; dst = w1b; off = g - 131072; }
    else                 { src = w2; dst = w2b; off = g - 262144; }
    float4 v0 = ((const float4*)src)[off * 2];
    float4 v1 = ((const float4*)src)[off * 2 + 1];
    u16x8 r;
    r[0] = f2bf(v0.x); r[1] = f2bf(v0.y); r[2] = f2bf(v0.z); r[3] = f2bf(v0.w);
    r[4] = f2bf(v1.x); r[5] = f2bf(v1.y); r[6] = f2bf(v1.z); r[7] = f2bf(v1.w);
    *(u16x8*)(dst + (size_t)off * 8) = r;
}

// ---------------------------------------------------------------------------
// Causal depthwise conv (4 taps) + SiLU on T layout.  (unchanged)
// ---------------------------------------------------------------------------
__global__ __launch_bounds__(256)
void conv_rows_kernel(const float* __restrict__ xzT,
                      const float* __restrict__ w,   // [1024][4]
                      const float* __restrict__ b,   // [1024]
                      float* __restrict__ xpcT) {
    const int d = blockIdx.y;
    const int l = blockIdx.x * 1024 + threadIdx.x * 4;
    const float4 wv = ((const float4*)w)[d];
    const float bias = b[d];
    const float* row = xzT + (size_t)d * L_SEQ;

    float4 cur  = *(const float4*)(row + l);
    float4 prev = (l == 0) ? make_float4(0.f, 0.f, 0.f, 0.f)
                           : *(const float4*)(row + l - 4);
    float e1 = prev.y, e2 = prev.z, e3 = prev.w;
    float e4 = cur.x, e5 = cur.y, e6 = cur.z, e7 = cur.w;
    float4 r;
    r.x = bias + wv.x * e1 + wv.y * e2 + wv.z * e3 + wv.w * e4;
    r.y = bias + wv.x * e2 + wv.y * e3 + wv.z * e4 + wv.w * e5;
    r.z = bias + wv.x * e3 + wv.y * e4 + wv.z * e5 + wv.w * e6;
    r.w = bias + wv.x * e4 + wv.y * e5 + wv.z * e6 + wv.w * e7;
    r.x = r.x / (1.f + __expf(-r.x));
    r.y = r.y / (1.f + __expf(-r.y));
    r.z = r.z / (1.f + __expf(-r.z));
    r.w = r.w / (1.f + __expf(-r.w));
    *(float4*)(xpcT + (size_t)d * L_SEQ + l) = r;
}

// ---------------------------------------------------------------------------
// x_proj on T layout.  (unchanged)
// ---------------------------------------------------------------------------
__global__ __launch_bounds__(256)
void xproj_kernel(const float* __restrict__ xpcT,
                  const float* __restrict__ xw,    // [64][1024]
                  float* __restrict__ xdblT) {     // [64][2048]
    const int tid  = threadIdx.x;
    const int part = tid >> 7;
    const int e    = (tid >> 1) & 63;
    const int lc   = tid & 1;
    const int l0   = blockIdx.x * 8;

    const float* wrow = xw + (size_t)e * 1024 + part * 512;
    const float* xcol = xpcT + (size_t)part * 512 * L_SEQ + l0 + lc * 4;

    f32x4 acc = {0.f, 0.f, 0.f, 0.f};
#pragma unroll 4
    for (int k = 0; k < 512; k += 4) {
        float4 wv = *(const float4*)(wrow + k);
        f32x4 x0 = *(const f32x4*)(xcol + (size_t)(k + 0) * L_SEQ);
        f32x4 x1 = *(const f32x4*)(xcol + (size_t)(k + 1) * L_SEQ);
        f32x4 x2 = *(const f32x4*)(xcol + (size_t)(k + 2) * L_SEQ);
        f32x4 x3 = *(const f32x4*)(xcol + (size_t)(k + 3) * L_SEQ);
        acc += wv.x * x0 + wv.y * x1 + wv.z * x2 + wv.w * x3;
    }

    __shared__ f32x4 red[128];
    if (part == 1) red[(e << 1) | lc] = acc;
    __syncthreads();
    if (part == 0) {
        acc += red[(e << 1) | lc];
        *(f32x4*)(xdblT + (size_t)e * L_SEQ + l0 + lc * 4) = acc;
    }
}

// ---------------------------------------------------------------------------
// Chunked selective scan with fused dt_proj+softplus prologue and batched
// transposing-butterfly C-reduction.  Math identical to the verified 3-phase
// formulation.  2 channels/block, 512 blocks; 32 chunks x 64 steps.
// Output: ypreT[d][l] bf16 (coalesced).
// ---------------------------------------------------------------------------
#define NCHUNK 32

__global__ __launch_bounds__(1024, 4)
void scan_kernel(const float* __restrict__ xpcT,
                 const float* __restrict__ xzT,    // z rows at 1024+d
                 const float* __restrict__ xdblT,  // rows 0..31 dt, 32..47 B, 48..63 C
                 const float* __restrict__ dtw,    // [1024][32]
                 const float* __restrict__ dtb,    // [1024]
                 const float* __restrict__ A_log, const float* __restrict__ Dv,
                 u16* __restrict__ ypreT) {
    const int tid   = threadIdx.x;
    const int lane  = tid & 63;
    const int chunk = ((tid >> 6) << 1) | (lane >> 5);   // 0..31
    const int dl    = (lane >> 4) & 1;
    const int n     = lane & 15;
    const int li    = (dl << 4) | n;
    const int d0    = blockIdx.x * 2;
    const int d     = d0 + dl;
    const int lb    = chunk * 64;

    __shared__ float sDelta[2][L_SEQ];   // 16 KB
    __shared__ float s_y[2][L_SEQ];      // 16 KB
    __shared__ float sLog[NCHUNK][32];
    __shared__ float sP[NCHUNK][32];
    __shared__ float sH[NCHUNK][32];

    // ---- Prologue: dt_proj + softplus for both channels -> LDS ----
    {
        const int pdl = tid >> 9;          // 0..1
        const int pl  = (tid & 511) * 4;
        const int pd  = d0 + pdl;
        float wreg[32];
#pragma unroll
        for (int r = 0; r < 32; r += 4)
            *(float4*)&wreg[r] = *(const float4*)(dtw + (size_t)pd * 32 + r);
        const float bias = dtb[pd];
        f32x4 a = {bias, bias, bias, bias};
#pragma unroll 8
        for (int r = 0; r < 32; r++) {
            f32x4 xv = *(const f32x4*)(xdblT + (size_t)r * L_SEQ + pl);
            a += wreg[r] * xv;
        }
        f32x4 o;
#pragma unroll
        for (int k = 0; k < 4; k++)
            o[k] = fmaxf(a[k], 0.f) + log1pf(expf(-fabsf(a[k])));
        *(f32x4*)&sDelta[pdl][pl] = o;
    }
    __syncthreads();

    const float Aneg = -__expf(A_log[d * D_STATE + n]);
    const float Dd   = Dv[d];
    const f32x4* dls = (const f32x4*)&sDelta[dl][lb];

    // ---- Phase A: chunk log-decay sum ----
    const float clipLog = -13.815511f;   // logf(1e-6f)
    float s = 0.f;
#pragma unroll 4
    for (int i = 0; i < 16; i++) {
        f32x4 d4 = dls[i];
#pragma unroll
        for (int k = 0; k < 4; k++) s += fmaxf(d4[k] * Aneg, clipLog);
    }
    sLog[chunk][li] = s;
    sP[chunk][li]   = __expf(s);
    __syncthreads();

    float lsum = 0.f;
    for (int v = 0; v < chunk; v++) lsum += sLog[v][li];
    const float cAs = __expf(lsum);

    // ---- Phase B: local accumulation with known cA_start ----
    const f32x4* xT4 = (const f32x4*)(xpcT  + (size_t)d * L_SEQ + lb);
    const f32x4* bT4 = (const f32x4*)(xdblT + (size_t)(32 + n) * L_SEQ + lb);
    const f32x4* cT4 = (const f32x4*)(xdblT + (size_t)(48 + n) * L_SEQ + lb);

    float hloc = 0.f, cA = cAs;
#pragma unroll 4
    for (int i = 0; i < 16; i++) {
        f32x4 d4 = dls[i], x4 = xT4[i], b4 = bT4[i];
#pragma unroll
        for (int k = 0; k < 4; k++) {
            float dA = fmaxf(__expf(d4[k] * Aneg), 1e-6f);
            float g  = cA * __builtin_amdgcn_rcpf(cA + 1e-8f);
            hloc = dA * hloc + (dA * g) * (d4[k] * b4[k] * x4[k]);
            cA *= dA;
        }
    }
    sH[chunk][li] = hloc;
    __syncthreads();

    float h = 0.f;
    for (int v = 0; v < chunk; v++) h = sP[v][li] * h + sH[v][li];

    // ---- Phase C: full recurrence + batched 16-lane reduce ----
    cA = cAs;
    const float* xrow = xpcT + (size_t)d * L_SEQ;
    const float* zrow = xzT + (size_t)(1024 + d) * L_SEQ;
#pragma unroll 1
    for (int b = 0; b < 4; b++) {
        float v[16];
#pragma unroll
        for (int i = 0; i < 4; i++) {
            const int idx = b * 4 + i;
            f32x4 d4 = dls[idx], x4 = xT4[idx], b4 = bT4[idx], c4 = cT4[idx];
#pragma unroll
            for (int k = 0; k < 4; k++) {
                float dA = fmaxf(__expf(d4[k] * Aneg), 1e-6f);
                float g  = cA * __builtin_amdgcn_rcpf(cA + 1e-8f);
                h  = dA * h + (dA * g) * (d4[k] * b4[k] * x4[k]);
                cA *= dA;
                v[i * 4 + k] = h * c4[k];
            }
        }
        // transposing butterfly: lane n ends with y_{lb + b*16 + n} in v[0]
#pragma unroll
        for (int m = 8; m >= 1; m >>= 1) {
#pragma unroll
            for (int j = 0; j < m; j++) {
                float send = (n & m) ? v[j] : v[j + m];
                float keep = (n & m) ? v[j + m] : v[j];
                v[j] = keep + __shfl_xor(send, m);
            }
        }
        const int t = lb + b * 16 + n;
        float xv = xrow[t];
        float zv = zrow[t];
        float sz = zv * __builtin_amdgcn_rcpf(1.f + __expf(-zv));
        s_y[dl][t] = (v[0] + xv * Dd) * sz;
    }
    __syncthreads();

    // coalesced writeout: ypreT[d][l] bf16
    {
        const int rdl = tid >> 9;
        const int pos = (tid & 511) * 4;
        f32x4 v = *(const f32x4*)&s_y[rdl][pos];
        ushort4 o;
        o.x = f2bf(v[0]); o.y = f2bf(v[1]); o.z = f2bf(v[2]); o.w = f2bf(v[3]);
        *(ushort4*)(ypreT + (size_t)(d0 + rdl) * L_SEQ + pos) = o;
    }
}

// ---------------------------------------------------------------------------
// bf16 64x64 tile transpose: ypreT[1024 d][2048 l] -> ypre[2048 l][1024 d]
// ---------------------------------------------------------------------------
__global__ __launch_bounds__(256)
void trans_bf16_kernel(const u16* __restrict__ src, u16* __restrict__ dst) {
    __shared__ u16 t[64][72];
    const int d0 = blockIdx.x * 64, l0 = blockIdx.y * 64;
    const int r = threadIdx.x >> 3;
    const int c = (threadIdx.x & 7) * 8;
#pragma unroll
    for (int rr = r; rr < 64; rr += 32)
        *(u16x8*)&t[rr][c] = *(const u16x8*)(src + (size_t)(d0 + rr) * L_SEQ + l0 + c);
    __syncthreads();
#pragma unroll
    for (int rr = r; rr < 64; rr += 32) {
        u16x8 v;
#pragma unroll
        for (int j = 0; j < 8; j++) v[j] = t[c + j][rr];
        *(u16x8*)(dst + (size_t)(l0 + rr) * D_INNER + d0 + c) = v;
    }
}

// ---------------------------------------------------------------------------
extern "C" void kernel_launch(void* const* d_in, const int* in_sizes, int n_in,
                              void* d_out, int out_size, void* d_ws, size_t ws_size,
                              hipStream_t stream) {
    const float* x          = (const float*)d_in[0];
    const float* in_proj_w  = (const float*)d_in[1];
    const float* conv_w     = (const float*)d_in[2];
    const float* conv_b     = (const float*)d_in[3];
    const float* x_proj_w   = (const float*)d_in[4];
    const float* dt_proj_w  = (const float*)d_in[5];
    const float* dt_proj_b  = (const float*)d_in[6];
    const float* A_log      = (const float*)d_in[7];
    const float* Dv         = (const float*)d_in[8];
    const float* out_proj_w = (const float*)d_in[9];
    float* out = (float*)d_out;
    float* ws  = (float*)d_ws;

    // workspace (float offsets):
    float* xzT    = ws;                        // [2048 e][2048 l] f32
    float* xpcT   = ws + 4194304;              // [1024][2048] f32
    float* xdblT  = ws + 6291456;              // [64][2048]   f32
    u16*   ypreT  = (u16*)(ws + 6422528);      // [1024][2048] bf16
    u16*   ypre   = (u16*)(ws + 7471104);      // [2048][1024] bf16
    u16*   xb     = (u16*)(ws + 8519680);      // [2048][512]  bf16
    u16*   w1b    = (u16*)(ws + 9043968);      // [2048][512]  bf16
    u16*   w2b    = (u16*)(ws + 9568256);      // [512][1024]  bf16

    // 0. cast x, in_proj_w, out_proj_w to bf16
    cast3_kernel<<<1280, 256, 0, stream>>>(x, in_proj_w, out_proj_w, xb, w1b, w2b);

    // 1. in_proj, transposed output: xzT = in_proj_w @ x^T
    gemm_mfma_nt<128, 128><<<dim3(2048 / 128, 2048 / 128), 256, 0, stream>>>(
        w1b, xb, xzT, 2 * D_INNER, L_SEQ, D_MODEL, L_SEQ);

    // 2. conv + silu on rows -> xpcT
    conv_rows_kernel<<<dim3(2, 1024), 256, 0, stream>>>(xzT, conv_w, conv_b, xpcT);

    // 3. x_proj -> xdblT
    xproj_kernel<<<256, 256, 0, stream>>>(xpcT, x_proj_w, xdblT);

    // 4. scan (fused dt_proj/softplus + D skip + silu(z) gate) -> ypreT
    scan_kernel<<<512, 1024, 0, stream>>>(xpcT, xzT, xdblT, dt_proj_w, dt_proj_b,
                                          A_log, Dv, ypreT);

    // 5. transpose ypreT -> ypre [l][d]
    trans_bf16_kernel<<<dim3(16, 32), 256, 0, stream>>>(ypreT, ypre);

    // 6. out_proj (bf16 MFMA): out = ypre @ out_proj_w^T
    gemm_mfma_nt<64, 64><<<dim3(512 / 64, 2048 / 64), 256, 0, stream>>>(
        ypre, w2b, out, L_SEQ, D_MODEL, D_INNER, D_MODEL);
}

// Round 7
// 178.928 us; speedup vs baseline: 1.1444x; 1.1444x over previous
//
#include <hip/hip_runtime.h>
#include <hip/hip_bf16.h>

// Problem constants (B=1)
#define L_SEQ   2048
#define D_MODEL 512
#define D_INNER 1024
#define D_STATE 16
#define DT_RANK 32

typedef unsigned short u16;
typedef short bf16x8 __attribute__((ext_vector_type(8)));
typedef float f32x4  __attribute__((ext_vector_type(4)));
typedef unsigned short u16x8 __attribute__((ext_vector_type(8)));

__device__ __forceinline__ u16 f2bf(float f) {
    union { float f; unsigned u; } x; x.f = f;
    unsigned r = x.u + 0x7FFFu + ((x.u >> 16) & 1u);
    return (u16)(r >> 16);
}

__device__ __forceinline__ void gload_lds16(const void* g, void* l) {
    __builtin_amdgcn_global_load_lds((const __attribute__((address_space(1))) void*)g,
                                     (__attribute__((address_space(3))) void*)l, 16, 0, 0);
}

// ---------------------------------------------------------------------------
// bf16 MFMA GEMM (NT):  C[m][n] = sum_k A[m*K+k]*B[n*K+k], C f32.  (verified)
// 256 thr = 4 waves (2x2).  Now launched with small tiles for co-residency:
// 64x64 -> 16 KB LDS -> 4 blocks/CU;  64x32 -> 12 KB -> 4+/CU.
// ---------------------------------------------------------------------------
template<int BM, int BN>
__global__ __launch_bounds__(256)
void gemm_mfma_nt(const u16* __restrict__ A, const u16* __restrict__ B,
                  float* __restrict__ C, int M, int N, int K, int ldc) {
    constexpr int FM = BM / 32;
    constexpr int FN = BN / 32;
    __shared__ u16 lA[BM * 64];
    __shared__ u16 lB[BN * 64];

    const int tid  = threadIdx.x;
    const int lane = tid & 63;
    const int w    = tid >> 6;
    const int wr   = w >> 1, wc = w & 1;
    const int m0 = blockIdx.y * BM;
    const int n0 = blockIdx.x * BN;

    f32x4 acc[FM][FN];
#pragma unroll
    for (int m = 0; m < FM; m++)
#pragma unroll
        for (int n = 0; n < FN; n++) acc[m][n] = (f32x4){0.f, 0.f, 0.f, 0.f};

    int offA[FM][2], offB[FN][2];
#pragma unroll
    for (int m = 0; m < FM; m++) {
        int r = wr * (BM / 2) + m * 16 + (lane & 15);
#pragma unroll
        for (int s = 0; s < 2; s++) {
            int kb = s * 4 + (lane >> 4);
            offA[m][s] = r * 128 + ((kb ^ (r & 7)) << 4);
        }
    }
#pragma unroll
    for (int n = 0; n < FN; n++) {
        int r = wc * (BN / 2) + n * 16 + (lane & 15);
#pragma unroll
        for (int s = 0; s < 2; s++) {
            int kb = s * 4 + (lane >> 4);
            offB[n][s] = r * 128 + ((kb ^ (r & 7)) << 4);
        }
    }

    const int ldsbase = (tid & 192) * 16;

    for (int k0 = 0; k0 < K; k0 += 64) {
        __syncthreads();
#pragma unroll
        for (int i = 0; i < BM / 32; i++) {
            int o = i * 4096 + tid * 16;
            int r = o >> 7;
            int kb = ((o >> 4) & 7) ^ (r & 7);
            gload_lds16(A + (size_t)(m0 + r) * K + k0 + kb * 8,
                        (char*)lA + i * 4096 + ldsbase);
        }
#pragma unroll
        for (int i = 0; i < BN / 32; i++) {
            int o = i * 4096 + tid * 16;
            int r = o >> 7;
            int kb = ((o >> 4) & 7) ^ (r & 7);
            gload_lds16(B + (size_t)(n0 + r) * K + k0 + kb * 8,
                        (char*)lB + i * 4096 + ldsbase);
        }
        __syncthreads();

#pragma unroll
        for (int s = 0; s < 2; s++) {
            bf16x8 av[FM], bv[FN];
#pragma unroll
            for (int m = 0; m < FM; m++)
                av[m] = *(const bf16x8*)((const char*)lA + offA[m][s]);
#pragma unroll
            for (int n = 0; n < FN; n++)
                bv[n] = *(const bf16x8*)((const char*)lB + offB[n][s]);
#pragma unroll
            for (int m = 0; m < FM; m++)
#pragma unroll
                for (int n = 0; n < FN; n++)
                    acc[m][n] = __builtin_amdgcn_mfma_f32_16x16x32_bf16(
                        av[m], bv[n], acc[m][n], 0, 0, 0);
        }
    }

    const int rb = (lane >> 4) * 4;
    const int cb = lane & 15;
#pragma unroll
    for (int m = 0; m < FM; m++)
#pragma unroll
        for (int n = 0; n < FN; n++) {
            int col = n0 + wc * (BN / 2) + n * 16 + cb;
#pragma unroll
            for (int j = 0; j < 4; j++) {
                int row = m0 + wr * (BM / 2) + m * 16 + rb + j;
                C[(size_t)row * ldc + col] = acc[m][n][j];
            }
        }
}

// ---------------------------------------------------------------------------
// Fused f32->bf16 cast of x, in_proj_w, out_proj_w.  (unchanged)
// ---------------------------------------------------------------------------
__global__ __launch_bounds__(256)
void cast3_kernel(const float* __restrict__ x, const float* __restrict__ w1,
                  const float* __restrict__ w2,
                  u16* __restrict__ xb, u16* __restrict__ w1b, u16* __restrict__ w2b) {
    int g = blockIdx.x * 256 + threadIdx.x;
    const float* src; u16* dst; int off;
    if (g < 131072)      { src = x;  dst = xb;  off = g; }
    else if (g < 262144) { src = w1; dst = w1b; off = g - 131072; }
    else                 { src = w2; dst = w2b; off = g - 262144; }
    float4 v0 = ((const float4*)src)[off * 2];
    float4 v1 = ((const float4*)src)[off * 2 + 1];
    u16x8 r;
    r[0] = f2bf(v0.x); r[1] = f2bf(v0.y); r[2] = f2bf(v0.z); r[3] = f2bf(v0.w);
    r[4] = f2bf(v1.x); r[5] = f2bf(v1.y); r[6] = f2bf(v1.z); r[7] = f2bf(v1.w);
    *(u16x8*)(dst + (size_t)off * 8) = r;
}

// ---------------------------------------------------------------------------
// Causal depthwise conv (4 taps) + SiLU on T layout.  (unchanged)
// ---------------------------------------------------------------------------
__global__ __launch_bounds__(256)
void conv_rows_kernel(const float* __restrict__ xzT,
                      const float* __restrict__ w,   // [1024][4]
                      const float* __restrict__ b,   // [1024]
                      float* __restrict__ xpcT) {
    const int d = blockIdx.y;
    const int l = blockIdx.x * 1024 + threadIdx.x * 4;
    const float4 wv = ((const float4*)w)[d];
    const float bias = b[d];
    const float* row = xzT + (size_t)d * L_SEQ;

    float4 cur  = *(const float4*)(row + l);
    float4 prev = (l == 0) ? make_float4(0.f, 0.f, 0.f, 0.f)
                           : *(const float4*)(row + l - 4);
    float e1 = prev.y, e2 = prev.z, e3 = prev.w;
    float e4 = cur.x, e5 = cur.y, e6 = cur.z, e7 = cur.w;
    float4 r;
    r.x = bias + wv.x * e1 + wv.y * e2 + wv.z * e3 + wv.w * e4;
    r.y = bias + wv.x * e2 + wv.y * e3 + wv.z * e4 + wv.w * e5;
    r.z = bias + wv.x * e3 + wv.y * e4 + wv.z * e5 + wv.w * e6;
    r.w = bias + wv.x * e4 + wv.y * e5 + wv.z * e6 + wv.w * e7;
    r.x = r.x / (1.f + __expf(-r.x));
    r.y = r.y / (1.f + __expf(-r.y));
    r.z = r.z / (1.f + __expf(-r.z));
    r.w = r.w / (1.f + __expf(-r.w));
    *(float4*)(xpcT + (size_t)d * L_SEQ + l) = r;
}

// ---------------------------------------------------------------------------
// x_proj on T layout.  (unchanged)
// ---------------------------------------------------------------------------
__global__ __launch_bounds__(256)
void xproj_kernel(const float* __restrict__ xpcT,
                  const float* __restrict__ xw,    // [64][1024]
                  float* __restrict__ xdblT) {     // [64][2048]
    const int tid  = threadIdx.x;
    const int part = tid >> 7;
    const int e    = (tid >> 1) & 63;
    const int lc   = tid & 1;
    const int l0   = blockIdx.x * 8;

    const float* wrow = xw + (size_t)e * 1024 + part * 512;
    const float* xcol = xpcT + (size_t)part * 512 * L_SEQ + l0 + lc * 4;

    f32x4 acc = {0.f, 0.f, 0.f, 0.f};
#pragma unroll 4
    for (int k = 0; k < 512; k += 4) {
        float4 wv = *(const float4*)(wrow + k);
        f32x4 x0 = *(const f32x4*)(xcol + (size_t)(k + 0) * L_SEQ);
        f32x4 x1 = *(const f32x4*)(xcol + (size_t)(k + 1) * L_SEQ);
        f32x4 x2 = *(const f32x4*)(xcol + (size_t)(k + 2) * L_SEQ);
        f32x4 x3 = *(const f32x4*)(xcol + (size_t)(k + 3) * L_SEQ);
        acc += wv.x * x0 + wv.y * x1 + wv.z * x2 + wv.w * x3;
    }

    __shared__ f32x4 red[128];
    if (part == 1) red[(e << 1) | lc] = acc;
    __syncthreads();
    if (part == 0) {
        acc += red[(e << 1) | lc];
        *(f32x4*)(xdblT + (size_t)e * L_SEQ + l0 + lc * 4) = acc;
    }
}

// ---------------------------------------------------------------------------
// Chunked selective scan (round-5 proven body) + low-register dt_proj fusion
// (weights via LDS broadcast) + bank-staggered sDelta + coalesced bf16 out.
// 2 channels/block, 512 blocks; 32 chunks x 64 steps.
// ---------------------------------------------------------------------------
#define NCHUNK 32
#define DSTR   2176   // per-dl stride in sDelta (32 chunks * 68)

__global__ __launch_bounds__(1024)
void scan_kernel(const float* __restrict__ xpcT,
                 const float* __restrict__ xzT,    // z rows at 1024+d
                 const float* __restrict__ xdblT,  // rows 0..31 dt, 32..47 B, 48..63 C
                 const float* __restrict__ dtw,    // [1024][32]
                 const float* __restrict__ dtb,    // [1024]
                 const float* __restrict__ A_log, const float* __restrict__ Dv,
                 u16* __restrict__ ypreT) {
    const int tid   = threadIdx.x;
    const int lane  = tid & 63;
    const int chunk = ((tid >> 6) << 1) | (lane >> 5);   // 0..31
    const int dl    = (lane >> 4) & 1;
    const int n     = lane & 15;
    const int li    = (dl << 4) | n;
    const int d0    = blockIdx.x * 2;
    const int d     = d0 + dl;
    const int lb    = chunk * 64;

    __shared__ float sW[2][32];
    __shared__ float sDelta[2][DSTR];    // chunk stride 68 -> 2-way max
    __shared__ float s_y[2][2064];
    __shared__ float sLog[NCHUNK][32];
    __shared__ float sP[NCHUNK][32];
    __shared__ float sH[NCHUNK][32];

    if (tid < 64) sW[tid >> 5][tid & 31] = dtw[(size_t)(d0 + (tid >> 5)) * 32 + (tid & 31)];
    __syncthreads();

    // ---- Prologue: dt_proj + softplus for both channels -> sDelta (LDS) ----
    {
        const int pdl = tid >> 9;              // 0..1 (wave-uniform)
        const int pl  = (tid & 511) * 4;
        const float bias = dtb[d0 + pdl];
        f32x4 a = {bias, bias, bias, bias};
        const float* xb_ = xdblT + pl;
#pragma unroll 8
        for (int r = 0; r < 32; r++) {
            f32x4 xv = *(const f32x4*)(xb_ + (size_t)r * L_SEQ);
            a += sW[pdl][r] * xv;
        }
        f32x4 o;
#pragma unroll
        for (int k = 0; k < 4; k++)
            o[k] = fmaxf(a[k], 0.f) + log1pf(expf(-fabsf(a[k])));
        const int pc = pl >> 6, pt = pl & 63;
        *(f32x4*)&sDelta[pdl][pc * 68 + pt] = o;
    }
    __syncthreads();

    const float Aneg = -__expf(A_log[d * D_STATE + n]);
    const float Dd   = Dv[d];
    const float* dls = &sDelta[dl][chunk * 68];

    // ---- Phase A: chunk log-decay sum ----
    const float clipLog = -13.815511f;   // logf(1e-6f)
    float s = 0.f;
#pragma unroll 4
    for (int i = 0; i < 16; i++) {
        f32x4 d4 = *(const f32x4*)(dls + i * 4);
#pragma unroll
        for (int k = 0; k < 4; k++) s += fmaxf(d4[k] * Aneg, clipLog);
    }
    sLog[chunk][li] = s;
    sP[chunk][li]   = __expf(s);
    __syncthreads();

    float lsum = 0.f;
    for (int v = 0; v < chunk; v++) lsum += sLog[v][li];
    const float cAs = __expf(lsum);

    // ---- Phase B: local accumulation with known cA_start ----
    const f32x4* xT4 = (const f32x4*)(xpcT  + (size_t)d * L_SEQ + lb);
    const f32x4* bT4 = (const f32x4*)(xdblT + (size_t)(32 + n) * L_SEQ + lb);
    const f32x4* cT4 = (const f32x4*)(xdblT + (size_t)(48 + n) * L_SEQ + lb);

    float hloc = 0.f, cA = cAs;
#pragma unroll 4
    for (int i = 0; i < 16; i++) {
        f32x4 d4 = *(const f32x4*)(dls + i * 4);
        f32x4 x4 = xT4[i], b4 = bT4[i];
#pragma unroll
        for (int k = 0; k < 4; k++) {
            float dA = fmaxf(__expf(d4[k] * Aneg), 1e-6f);
            float g  = cA * __builtin_amdgcn_rcpf(cA + 1e-8f);
            hloc = dA * hloc + (dA * g) * (d4[k] * b4[k] * x4[k]);
            cA *= dA;
        }
    }
    sH[chunk][li] = hloc;
    __syncthreads();

    float h = 0.f;
    for (int v = 0; v < chunk; v++) h = sP[v][li] * h + sH[v][li];

    // ---- Phase C: full recurrence + per-step 16-lane shfl reduce ----
    cA = cAs;
    const float* xrow = xpcT + (size_t)d * L_SEQ;
    const float* zrow = xzT + (size_t)(1024 + d) * L_SEQ;
#pragma unroll 4
    for (int i = 0; i < 16; i++) {
        f32x4 d4 = *(const f32x4*)(dls + i * 4);
        f32x4 x4 = xT4[i], b4 = bT4[i], c4 = cT4[i];
#pragma unroll
        for (int k = 0; k < 4; k++) {
            float dA = fmaxf(__expf(d4[k] * Aneg), 1e-6f);
            float g  = cA * __builtin_amdgcn_rcpf(cA + 1e-8f);
            h  = dA * h + (dA * g) * (d4[k] * b4[k] * x4[k]);
            cA *= dA;
            float p = h * c4[k];
            p += __shfl_xor(p, 1);
            p += __shfl_xor(p, 2);
            p += __shfl_xor(p, 4);
            p += __shfl_xor(p, 8);
            if (n == 0) {
                const int t = lb + 4 * i + k;
                float zv = zrow[t];
                float sz = zv * __builtin_amdgcn_rcpf(1.f + __expf(-zv));
                s_y[dl][t] = (p + xrow[t] * Dd) * sz;
            }
        }
    }
    __syncthreads();

    // coalesced writeout: ypreT[d][l] bf16
    {
        const int rdl = tid >> 9;
        const int pos = (tid & 511) * 4;
        f32x4 v = *(const f32x4*)&s_y[rdl][pos];
        ushort4 o;
        o.x = f2bf(v[0]); o.y = f2bf(v[1]); o.z = f2bf(v[2]); o.w = f2bf(v[3]);
        *(ushort4*)(ypreT + (size_t)(d0 + rdl) * L_SEQ + pos) = o;
    }
}

// ---------------------------------------------------------------------------
// bf16 64x64 tile transpose: ypreT[1024 d][2048 l] -> ypre[2048 l][1024 d]
// ---------------------------------------------------------------------------
__global__ __launch_bounds__(256)
void trans_bf16_kernel(const u16* __restrict__ src, u16* __restrict__ dst) {
    __shared__ u16 t[64][72];
    const int d0 = blockIdx.x * 64, l0 = blockIdx.y * 64;
    const int r = threadIdx.x >> 3;
    const int c = (threadIdx.x & 7) * 8;
#pragma unroll
    for (int rr = r; rr < 64; rr += 32)
        *(u16x8*)&t[rr][c] = *(const u16x8*)(src + (size_t)(d0 + rr) * L_SEQ + l0 + c);
    __syncthreads();
#pragma unroll
    for (int rr = r; rr < 64; rr += 32) {
        u16x8 v;
#pragma unroll
        for (int j = 0; j < 8; j++) v[j] = t[c + j][rr];
        *(u16x8*)(dst + (size_t)(l0 + rr) * D_INNER + d0 + c) = v;
    }
}

// ---------------------------------------------------------------------------
extern "C" void kernel_launch(void* const* d_in, const int* in_sizes, int n_in,
                              void* d_out, int out_size, void* d_ws, size_t ws_size,
                              hipStream_t stream) {
    const float* x          = (const float*)d_in[0];
    const float* in_proj_w  = (const float*)d_in[1];
    const float* conv_w     = (const float*)d_in[2];
    const float* conv_b     = (const float*)d_in[3];
    const float* x_proj_w   = (const float*)d_in[4];
    const float* dt_proj_w  = (const float*)d_in[5];
    const float* dt_proj_b  = (const float*)d_in[6];
    const float* A_log      = (const float*)d_in[7];
    const float* Dv         = (const float*)d_in[8];
    const float* out_proj_w = (const float*)d_in[9];
    float* out = (float*)d_out;
    float* ws  = (float*)d_ws;

    // workspace (float offsets):
    float* xzT    = ws;                        // [2048 e][2048 l] f32
    float* xpcT   = ws + 4194304;              // [1024][2048] f32
    float* xdblT  = ws + 6291456;              // [64][2048]   f32
    u16*   ypreT  = (u16*)(ws + 6422528);      // [1024][2048] bf16
    u16*   ypre   = (u16*)(ws + 7471104);      // [2048][1024] bf16
    u16*   xb     = (u16*)(ws + 8519680);      // [2048][512]  bf16
    u16*   w1b    = (u16*)(ws + 9043968);      // [2048][512]  bf16
    u16*   w2b    = (u16*)(ws + 9568256);      // [512][1024]  bf16

    // 0. cast x, in_proj_w, out_proj_w to bf16
    cast3_kernel<<<1280, 256, 0, stream>>>(x, in_proj_w, out_proj_w, xb, w1b, w2b);

    // 1. in_proj, transposed output: xzT = in_proj_w @ x^T
    //    64x64 tiles -> 1024 blocks (4/CU co-resident)
    gemm_mfma_nt<64, 64><<<dim3(2048 / 64, 2048 / 64), 256, 0, stream>>>(
        w1b, xb, xzT, 2 * D_INNER, L_SEQ, D_MODEL, L_SEQ);

    // 2. conv + silu on rows -> xpcT
    conv_rows_kernel<<<dim3(2, 1024), 256, 0, stream>>>(xzT, conv_w, conv_b, xpcT);

    // 3. x_proj -> xdblT
    xproj_kernel<<<256, 256, 0, stream>>>(xpcT, x_proj_w, xdblT);

    // 4. scan (fused dt_proj/softplus + D skip + silu(z) gate) -> ypreT
    scan_kernel<<<512, 1024, 0, stream>>>(xpcT, xzT, xdblT, dt_proj_w, dt_proj_b,
                                          A_log, Dv, ypreT);

    // 5. transpose ypreT -> ypre [l][d]
    trans_bf16_kernel<<<dim3(16, 32), 256, 0, stream>>>(ypreT, ypre);

    // 6. out_proj: 64x32 tiles -> 512 blocks (2/CU)
    gemm_mfma_nt<64, 32><<<dim3(512 / 32, 2048 / 64), 256, 0, stream>>>(
        ypre, w2b, out, L_SEQ, D_MODEL, D_INNER, D_MODEL);
}